// Round 1
// baseline (64.168 us; speedup 1.0000x reference)
//
#include <hip/hip_runtime.h>
#include <hip/hip_bf16.h>

#define M 256
#define NOUT 1024
#define KTOT 16384
#define RANK 16
#define BN 32
#define BK 32
#define NKC 16
#define NIT 32   // (KTOT/NKC)/BK = 1024/32

typedef __attribute__((ext_vector_type(8))) short bf16x8_t;
typedef __attribute__((ext_vector_type(4))) float f32x4_t;
typedef __attribute__((ext_vector_type(8))) unsigned short u16x8_t;
typedef __attribute__((ext_vector_type(4))) unsigned short u16x4_t;

static __device__ __forceinline__ unsigned short f2bf(float f) {
  unsigned u = __builtin_bit_cast(unsigned, f);
  u += 0x7FFFu + ((u >> 16) & 1u);   // round-to-nearest-even
  return (unsigned short)(u >> 16);
}

// X[b][k] = input[b][k>>4] * coef[b][k&15], bf16, k = i*16+r matches weight[o][i][r] flatten
__global__ __launch_bounds__(256) void build_x_kernel(
    const float* __restrict__ input, const float* __restrict__ coef,
    unsigned short* __restrict__ X)
{
  int idx = blockIdx.x * 256 + threadIdx.x;   // idx = b*1024 + i
  int b = idx >> 10;
  float in = input[idx];
  const float* c = coef + b * RANK;
  u16x8_t lo, hi;
  #pragma unroll
  for (int r = 0; r < 8; ++r) lo[r] = f2bf(in * c[r]);
  #pragma unroll
  for (int r = 0; r < 8; ++r) hi[r] = f2bf(in * c[8 + r]);
  u16x8_t* dst = (u16x8_t*)(X + (size_t)idx * 16);
  dst[0] = lo;
  dst[1] = hi;
}

// Split-K GEMM: out_part[kc][b][o] = sum_{k in chunk kc} X[b][k] * W[o][k]
// Block: BM=256 (all rows), BN=32 cols, K-chunk = NIT*BK = 1024. 4 waves,
// wave w owns rows [w*64, w*64+64). acc: 4 m-frags x 2 n-frags of 16x16.
__global__ __launch_bounds__(256, 2) void gemm_part_kernel(
    const unsigned short* __restrict__ X, const float* __restrict__ W,
    float* __restrict__ part)
{
  // A LDS: k-grouped [kg(4)][row(256)][8 bf16] = 16 KB/buf
  // B LDS: k-grouped [kg(4)][col(32)][8 bf16]  =  2 KB/buf
  __shared__ unsigned short As[2][4 * 256 * 8];
  __shared__ unsigned short Bs[2][4 * 32 * 8];

  const int tid = threadIdx.x;
  const int wid = tid >> 6, lane = tid & 63;
  const int lg = lane >> 4, lr = lane & 15;
  const int nt = blockIdx.x, kc = blockIdx.y;
  const int o0 = nt * BN;
  const int kbase0 = kc * (NIT * BK);

  f32x4_t acc[4][2];
  #pragma unroll
  for (int a = 0; a < 4; ++a)
    #pragma unroll
    for (int q = 0; q < 2; ++q) acc[a][q] = (f32x4_t)(0.0f);

  // B staging coords: thread t covers W[o0 + (t>>3)][kb + (t&7)*4 .. +3]
  const int brow = tid >> 3, c4 = tid & 7;
  const int bs_off = ((c4 >> 1) * 32 + brow) * 8 + (c4 & 1) * 4;  // shorts within a buf

  // ---- prologue: stage it=0 into buf 0 ----
  {
    #pragma unroll
    for (int j = 0; j < 4; ++j) {
      int u = (wid * 4 + j) * 64 + lane;       // unit = kg*256 + row
      int row = u & 255, kg = u >> 8;
      const unsigned short* src = X + (size_t)row * KTOT + kbase0 + kg * 8;
      __builtin_amdgcn_global_load_lds(
          (const __attribute__((address_space(1))) unsigned int*)src,
          (__attribute__((address_space(3))) unsigned int*)&As[0][u * 8],
          16, 0, 0);
    }
    float4 bv = *(const float4*)(W + (size_t)(o0 + brow) * KTOT + kbase0 + c4 * 4);
    u16x4_t hv;
    hv[0] = f2bf(bv.x); hv[1] = f2bf(bv.y); hv[2] = f2bf(bv.z); hv[3] = f2bf(bv.w);
    *(u16x4_t*)&Bs[0][bs_off] = hv;
  }
  __syncthreads();

  int cur = 0;
  for (int it = 0; it < NIT; ++it) {
    const bool more = (it + 1 < NIT);
    float4 bv;
    if (more) {
      const int kb = kbase0 + (it + 1) * BK;
      #pragma unroll
      for (int j = 0; j < 4; ++j) {
        int u = (wid * 4 + j) * 64 + lane;
        int row = u & 255, kg = u >> 8;
        const unsigned short* src = X + (size_t)row * KTOT + kb + kg * 8;
        __builtin_amdgcn_global_load_lds(
            (const __attribute__((address_space(1))) unsigned int*)src,
            (__attribute__((address_space(3))) unsigned int*)&As[cur ^ 1][u * 8],
            16, 0, 0);
      }
      bv = *(const float4*)(W + (size_t)(o0 + brow) * KTOT + kb + c4 * 4);
    }

    // compute from buf `cur`
    bf16x8_t af[4], bfr[2];
    #pragma unroll
    for (int fm = 0; fm < 4; ++fm)
      af[fm] = *(const bf16x8_t*)&As[cur][(lg * 256 + wid * 64 + fm * 16 + lr) * 8];
    #pragma unroll
    for (int fn = 0; fn < 2; ++fn)
      bfr[fn] = *(const bf16x8_t*)&Bs[cur][(lg * 32 + fn * 16 + lr) * 8];
    #pragma unroll
    for (int fm = 0; fm < 4; ++fm)
      #pragma unroll
      for (int fn = 0; fn < 2; ++fn)
        acc[fm][fn] = __builtin_amdgcn_mfma_f32_16x16x32_bf16(af[fm], bfr[fn], acc[fm][fn], 0, 0, 0);

    if (more) {
      u16x4_t hv;
      hv[0] = f2bf(bv.x); hv[1] = f2bf(bv.y); hv[2] = f2bf(bv.z); hv[3] = f2bf(bv.w);
      *(u16x4_t*)&Bs[cur ^ 1][bs_off] = hv;
    }
    __syncthreads();
    cur ^= 1;
  }

  // ---- epilogue: write fp32 partials. C/D layout: col=lane&15, row=(lane>>4)*4+reg ----
  float* p = part + (size_t)kc * (M * NOUT);
  #pragma unroll
  for (int fm = 0; fm < 4; ++fm) {
    #pragma unroll
    for (int fn = 0; fn < 2; ++fn) {
      #pragma unroll
      for (int j = 0; j < 4; ++j) {
        int row = wid * 64 + fm * 16 + lg * 4 + j;
        int col = o0 + fn * 16 + lr;
        p[(size_t)row * NOUT + col] = acc[fm][fn][j];
      }
    }
  }
}

// out[b][o] = sum_kc part[kc][b][o] + sum_r bias[o][r]*coef[b][r]
__global__ __launch_bounds__(256) void reduce_bias_kernel(
    const float* __restrict__ part, const float* __restrict__ bias,
    const float* __restrict__ coef, float* __restrict__ out)
{
  int idx = blockIdx.x * 256 + threadIdx.x;   // idx = b*1024 + o
  int b = idx >> 10, o = idx & 1023;
  float s = 0.f;
  #pragma unroll
  for (int c = 0; c < NKC; ++c) s += part[(size_t)c * (M * NOUT) + idx];
  const f32x4_t* br = (const f32x4_t*)(bias + (size_t)o * RANK);
  const f32x4_t* cr = (const f32x4_t*)(coef + (size_t)b * RANK);
  float bb = 0.f;
  #pragma unroll
  for (int q = 0; q < 4; ++q) {
    f32x4_t bv = br[q], cv = cr[q];
    bb += bv[0] * cv[0] + bv[1] * cv[1] + bv[2] * cv[2] + bv[3] * cv[3];
  }
  out[idx] = s + bb;
}

extern "C" void kernel_launch(void* const* d_in, const int* in_sizes, int n_in,
                              void* d_out, int out_size, void* d_ws, size_t ws_size,
                              hipStream_t stream) {
  const float* input = (const float*)d_in[0];   // (256, 1024)
  const float* coef  = (const float*)d_in[1];   // (256, 16)
  const float* W     = (const float*)d_in[2];   // (1024, 1024, 16) -> (1024, 16384)
  const float* bias  = (const float*)d_in[3];   // (1024, 16)
  float* out = (float*)d_out;                   // (256, 1024)

  unsigned short* X = (unsigned short*)d_ws;                          // 8 MiB bf16
  float* part = (float*)((char*)d_ws + (size_t)M * KTOT * 2);         // 16 MiB fp32

  build_x_kernel<<<(M * 1024) / 256, 256, 0, stream>>>(input, coef, X);
  gemm_part_kernel<<<dim3(NOUT / BN, NKC), 256, 0, stream>>>(X, W, part);
  reduce_bias_kernel<<<(M * NOUT) / 256, 256, 0, stream>>>(part, bias, coef, out);
}

// Round 2
// 46.464 us; speedup vs baseline: 1.3810x; 1.3810x over previous
//
#include <hip/hip_runtime.h>
#include <hip/hip_bf16.h>

#define M 256
#define NOUT 1024
#define KTOT 16384
#define RANK 16
#define NKC 32          // split-K factor (grid.y)
#define KCHUNK 512      // K per block = KTOT/NKC
#define BKC 64          // K per LDS stage
#define NCH 8           // KCHUNK/BKC
#define BN 128          // cols per block = 4 waves * 32
#define NTILE 8         // NOUT/BN

typedef __attribute__((ext_vector_type(8))) short bf16x8_t;
typedef __attribute__((ext_vector_type(4))) float f32x4_t;
typedef __attribute__((ext_vector_type(8))) unsigned short u16x8_t;

static __device__ __forceinline__ unsigned short f2bf(float f) {
  unsigned u = __builtin_bit_cast(unsigned, f);
  u += 0x7FFFu + ((u >> 16) & 1u);   // round-to-nearest-even
  return (unsigned short)(u >> 16);
}
static __device__ __forceinline__ float bf2f(unsigned short h) {
  unsigned u = ((unsigned)h) << 16;
  return __builtin_bit_cast(float, u);
}

// X stored chunk-blocked + bank-swizzled:
//   element (b, k):  chunk = k>>6, u = (k&63)>>3, el = k&7
//   pos = (chunk*256 + b)*64 + ((u ^ (b&7)) * 8) + el        (bf16)
// so that linear global_load_lds of a chunk gives LDS rows of 128 B whose 16B
// slots are XOR-swizzled by (row&7)  -> conflict-free ds_read_b128 fragments.
__global__ __launch_bounds__(256) void build_x_kernel(
    const float* __restrict__ input, const float* __restrict__ coef,
    unsigned short* __restrict__ X)
{
  int idx = blockIdx.x * 256 + threadIdx.x;   // idx = b*1024 + i
  int b = idx >> 10, i = idx & 1023;
  float in = input[idx];
  const float* c = coef + b * RANK;
  u16x8_t lo, hi;
  #pragma unroll
  for (int r = 0; r < 8; ++r) lo[r] = f2bf(in * c[r]);
  #pragma unroll
  for (int r = 0; r < 8; ++r) hi[r] = f2bf(in * c[8 + r]);
  int chunk = i >> 2;            // (i*16) >> 6
  int u0 = (i & 3) * 2;          // first 16B slot index within the row
  size_t base = ((size_t)chunk * 256 + b) * 64;
  *(u16x8_t*)(X + base + (size_t)((u0    ) ^ (b & 7)) * 8) = lo;
  *(u16x8_t*)(X + base + (size_t)((u0 + 1) ^ (b & 7)) * 8) = hi;
}

// GEMM: part[kc][b][o] (bf16) = sum_{k in chunk kc} X[b][k] * W[o][k]
// Block: BM=256 (all M), BN=128 (wave w owns cols [o0+w*32, +32)), 4 waves.
// W (B-operand) loads go DIRECTLY global->reg in MFMA fragment layout
// (lane l = col l&15, k=(l>>4)*8..+7 : 8 contiguous floats of one W row),
// converted fp32->bf16 in-register. A (X) double-buffered in LDS per 64-k
// chunk via global_load_lds; one __syncthreads per chunk.
__global__ __launch_bounds__(256, 1) void gemm_kernel(
    const unsigned short* __restrict__ X, const float* __restrict__ W,
    unsigned short* __restrict__ part)
{
  __shared__ unsigned short As[2][256 * 64];   // 2 x 32 KB

  const int tid = threadIdx.x;
  const int wid = tid >> 6, lane = tid & 63;
  const int lr = lane & 15, lg = lane >> 4;
  const int kc = blockIdx.y;
  const int o0 = blockIdx.x * BN + wid * 32;
  const int ch0 = kc * NCH;                    // global 64-k chunk base
  const int kb0 = kc * KCHUNK;

  f32x4_t acc[16][2];
  #pragma unroll
  for (int a = 0; a < 16; ++a) {
    acc[a][0] = (f32x4_t)(0.0f);
    acc[a][1] = (f32x4_t)(0.0f);
  }

  const float* wrow0 = W + (size_t)(o0 + lr) * KTOT + lg * 8;        // fn=0
  const float* wrow1 = W + (size_t)(o0 + 16 + lr) * KTOT + lg * 8;   // fn=1

  float4 bq[2][2][2][2];   // [set][it][fn][half4] -- all statically indexed

  // ---- helpers as macros (keep everything statically indexed) ----
  #define STAGE(cch, buf)                                                     \
    {                                                                         \
      const unsigned short* srcb = X + (size_t)(ch0 + (cch)) * 16384;         \
      _Pragma("unroll")                                                       \
      for (int j = 0; j < 8; ++j) {                                           \
        __builtin_amdgcn_global_load_lds(                                     \
            (const __attribute__((address_space(1))) unsigned int*)           \
                (srcb + (size_t)(j * 256 + tid) * 8),                         \
            (__attribute__((address_space(3))) unsigned int*)                 \
                (&As[buf][(j * 256 + tid) * 8]),                              \
            16, 0, 0);                                                        \
      }                                                                       \
    }

  #define LOADB(set, cch)                                                     \
    {                                                                         \
      _Pragma("unroll")                                                       \
      for (int it = 0; it < 2; ++it) {                                        \
        int ko = kb0 + (cch) * BKC + it * 32;                                 \
        bq[set][it][0][0] = *(const float4*)(wrow0 + ko);                     \
        bq[set][it][0][1] = *(const float4*)(wrow0 + ko + 4);                 \
        bq[set][it][1][0] = *(const float4*)(wrow1 + ko);                     \
        bq[set][it][1][1] = *(const float4*)(wrow1 + ko + 4);                 \
      }                                                                       \
    }

  #define COMPUTE(cch, set, buf)                                              \
    {                                                                         \
      _Pragma("unroll")                                                       \
      for (int it = 0; it < 2; ++it) {                                        \
        bf16x8_t bf0, bf1;                                                    \
        _Pragma("unroll")                                                     \
        for (int e = 0; e < 4; ++e) {                                         \
          bf0[e]     = (short)f2bf(bq[set][it][0][0][e]);                     \
          bf0[e + 4] = (short)f2bf(bq[set][it][0][1][e]);                     \
          bf1[e]     = (short)f2bf(bq[set][it][1][0][e]);                     \
          bf1[e + 4] = (short)f2bf(bq[set][it][1][1][e]);                     \
        }                                                                     \
        _Pragma("unroll")                                                     \
        for (int fm = 0; fm < 16; ++fm) {                                     \
          int row = fm * 16 + lr;                                             \
          int slot = (it * 4 + lg) ^ (row & 7);                               \
          bf16x8_t av = *(const bf16x8_t*)&As[buf][row * 64 + slot * 8];      \
          acc[fm][0] = __builtin_amdgcn_mfma_f32_16x16x32_bf16(               \
              av, bf0, acc[fm][0], 0, 0, 0);                                  \
          acc[fm][1] = __builtin_amdgcn_mfma_f32_16x16x32_bf16(               \
              av, bf1, acc[fm][1], 0, 0, 0);                                  \
        }                                                                     \
      }                                                                       \
    }

  // ---- prologue: stage chunks 0,1; load B chunk 0 ----
  STAGE(0, 0)
  STAGE(1, 1)
  LOADB(0, 0)
  __syncthreads();

  // ---- main loop: fully unrolled so bq/As indices stay static ----
  #pragma unroll
  for (int c = 0; c < NCH; ++c) {
    if (c + 1 < NCH) LOADB((c + 1) & 1, c + 1)   // B prefetch, 1 chunk ahead
    COMPUTE(c, c & 1, c & 1)
    __syncthreads();                             // all waves done with buf c&1
    if (c + 2 < NCH) STAGE(c + 2, c & 1)         // A prefetch, 2 chunks ahead
  }

  // ---- epilogue: C/D layout col=lane&15, row=(lane>>4)*4+j ----
  unsigned short* p = part + (size_t)kc * (M * NOUT);
  #pragma unroll
  for (int fm = 0; fm < 16; ++fm) {
    #pragma unroll
    for (int fn = 0; fn < 2; ++fn) {
      #pragma unroll
      for (int j = 0; j < 4; ++j) {
        int b = fm * 16 + lg * 4 + j;
        int col = o0 + fn * 16 + lr;
        p[(size_t)b * NOUT + col] = f2bf(acc[fm][fn][j]);
      }
    }
  }
  #undef STAGE
  #undef LOADB
  #undef COMPUTE
}

// out[b][o] = sum_kc bf2f(part[kc][b][o]) + sum_r bias[o][r]*coef[b][r]
__global__ __launch_bounds__(256) void reduce_bias_kernel(
    const unsigned short* __restrict__ part, const float* __restrict__ bias,
    const float* __restrict__ coef, float* __restrict__ out)
{
  int t = blockIdx.x * 256 + threadIdx.x;
  int idx8 = t * 8;                       // 8 consecutive outputs, same b
  int b = idx8 >> 10, o = idx8 & 1023;

  float s[8];
  #pragma unroll
  for (int j = 0; j < 8; ++j) s[j] = 0.f;

  #pragma unroll
  for (int c = 0; c < NKC; ++c) {
    u16x8_t v = *(const u16x8_t*)(part + (size_t)c * (M * NOUT) + idx8);
    #pragma unroll
    for (int j = 0; j < 8; ++j) s[j] += bf2f(v[j]);
  }

  const f32x4_t* cr = (const f32x4_t*)(coef + (size_t)b * RANK);
  f32x4_t c0 = cr[0], c1 = cr[1], c2 = cr[2], c3 = cr[3];
  #pragma unroll
  for (int j = 0; j < 8; ++j) {
    const f32x4_t* br = (const f32x4_t*)(bias + (size_t)(o + j) * RANK);
    f32x4_t b0 = br[0], b1 = br[1], b2 = br[2], b3 = br[3];
    float bb = 0.f;
    #pragma unroll
    for (int e = 0; e < 4; ++e)
      bb += b0[e] * c0[e] + b1[e] * c1[e] + b2[e] * c2[e] + b3[e] * c3[e];
    s[j] += bb;
  }
  float4* dst = (float4*)(out + idx8);
  dst[0] = make_float4(s[0], s[1], s[2], s[3]);
  dst[1] = make_float4(s[4], s[5], s[6], s[7]);
}

extern "C" void kernel_launch(void* const* d_in, const int* in_sizes, int n_in,
                              void* d_out, int out_size, void* d_ws, size_t ws_size,
                              hipStream_t stream) {
  const float* input = (const float*)d_in[0];   // (256, 1024)
  const float* coef  = (const float*)d_in[1];   // (256, 16)
  const float* W     = (const float*)d_in[2];   // (1024, 1024, 16) -> (1024, 16384)
  const float* bias  = (const float*)d_in[3];   // (1024, 16)
  float* out = (float*)d_out;                   // (256, 1024)

  unsigned short* X    = (unsigned short*)d_ws;                        // 8 MiB bf16
  unsigned short* part = (unsigned short*)((char*)d_ws + (size_t)M * KTOT * 2); // 16 MiB bf16

  build_x_kernel<<<(M * 1024) / 256, 256, 0, stream>>>(input, coef, X);
  gemm_kernel<<<dim3(NTILE, NKC), 256, 0, stream>>>(X, W, part);
  reduce_bias_kernel<<<(M * NOUT) / (256 * 8), 256, 0, stream>>>(part, bias, coef, out);
}

// Round 3
// 42.236 us; speedup vs baseline: 1.5193x; 1.1001x over previous
//
#include <hip/hip_runtime.h>
#include <hip/hip_bf16.h>

#define M 256
#define NOUT 1024
#define KTOT 16384
#define RANK 16
#define NKC 32          // split-K factor (grid.y)
#define KCHUNK 512      // K per block = KTOT/NKC
#define BKC 64          // K per LDS stage (one chunk)
#define BN 64           // cols per block = 4 waves * 16
#define NTILE 16        // NOUT/BN

typedef __attribute__((ext_vector_type(8))) short bf16x8_t;
typedef __attribute__((ext_vector_type(4))) float f32x4_t;
typedef __attribute__((ext_vector_type(8))) unsigned short u16x8_t;

static __device__ __forceinline__ unsigned short f2bf(float f) {
  unsigned u = __builtin_bit_cast(unsigned, f);
  u += 0x7FFFu + ((u >> 16) & 1u);   // round-to-nearest-even
  return (unsigned short)(u >> 16);
}
static __device__ __forceinline__ float bf2f(unsigned short h) {
  unsigned u = ((unsigned)h) << 16;
  return __builtin_bit_cast(float, u);
}

// X stored chunk-blocked + bank-swizzled:
//   element (b, k):  chunk = k>>6, u = (k&63)>>3, el = k&7
//   pos = (chunk*256 + b)*64 + ((u ^ (b&7)) * 8) + el        (bf16)
// Linear global_load_lds of a chunk then yields LDS rows of 128 B whose 16B
// slots are XOR-swizzled by (row&7) -> conflict-free ds_read_b128 fragments.
__global__ __launch_bounds__(256) void build_x_kernel(
    const float* __restrict__ input, const float* __restrict__ coef,
    unsigned short* __restrict__ X)
{
  int idx = blockIdx.x * 256 + threadIdx.x;   // idx = b*1024 + i
  int b = idx >> 10, i = idx & 1023;
  float in = input[idx];
  const float* c = coef + b * RANK;
  u16x8_t lo, hi;
  #pragma unroll
  for (int r = 0; r < 8; ++r) lo[r] = f2bf(in * c[r]);
  #pragma unroll
  for (int r = 0; r < 8; ++r) hi[r] = f2bf(in * c[8 + r]);
  int chunk = i >> 2;            // (i*16) >> 6
  int u0 = (i & 3) * 2;          // first 16B slot index within the row
  size_t base = ((size_t)chunk * 256 + b) * 64;
  *(u16x8_t*)(X + base + (size_t)((u0    ) ^ (b & 7)) * 8) = lo;
  *(u16x8_t*)(X + base + (size_t)((u0 + 1) ^ (b & 7)) * 8) = hi;
}

// GEMM: part[kc][b][o] (bf16) = sum_{k in chunk kc} X[b][k] * W[o][k]
// BM=256 (all M), BN=64: wave w owns cols [o0+w*16, +16). 512 blocks, 2/CU.
// W loads go DIRECTLY global->reg in the MFMA B-fragment layout (lane l:
// col=l&15 -> row o0+w*16+lr; k=(l>>4)*8.. -> 8 contiguous floats of one W
// row), converted fp32->bf16 in-register. A (X) double-buffered in LDS per
// 64-k chunk via global_load_lds. Fully straight-line schedule: all register
// sets are NAMED variables, all LDS buffer indices are literals -- no
// runtime-indexed register arrays can exist (scratch-proof).
__global__ __launch_bounds__(256, 2) void gemm_kernel(
    const unsigned short* __restrict__ X, const float* __restrict__ W,
    unsigned short* __restrict__ part)
{
  __shared__ unsigned short As0[256 * 64];   // 32 KB
  __shared__ unsigned short As1[256 * 64];   // 32 KB

  const int tid = threadIdx.x;
  const int wid = tid >> 6, lane = tid & 63;
  const int lr = lane & 15, lg = lane >> 4;
  const int kc = blockIdx.y;
  const int o0 = blockIdx.x * BN + wid * 16;   // this wave's 16-col base
  const int ch0 = kc * (KCHUNK / BKC);         // global 64-k chunk base
  const int kb0 = kc * KCHUNK;

  f32x4_t acc[16];
  #pragma unroll
  for (int a = 0; a < 16; ++a) acc[a] = (f32x4_t)(0.0f);

  const float* wrow = W + (size_t)(o0 + lr) * KTOT + lg * 8;

  float4 bqA00, bqA01, bqA10, bqA11;
  float4 bqB00, bqB01, bqB10, bqB11;

  #define STAGE(cch, ASBUF)                                                   \
    {                                                                         \
      const unsigned short* srcb = X + (size_t)(ch0 + (cch)) * 16384;         \
      _Pragma("unroll")                                                       \
      for (int j = 0; j < 8; ++j) {                                           \
        __builtin_amdgcn_global_load_lds(                                     \
            (const __attribute__((address_space(1))) unsigned int*)           \
                (srcb + (size_t)(j * 256 + tid) * 8),                         \
            (__attribute__((address_space(3))) unsigned int*)                 \
                (&ASBUF[(j * 256 + tid) * 8]),                                \
            16, 0, 0);                                                        \
      }                                                                       \
    }

  #define LOADB(S, cch)                                                       \
    {                                                                         \
      int ko = kb0 + (cch) * BKC;                                             \
      bq##S##00 = *(const float4*)(wrow + ko);                                \
      bq##S##01 = *(const float4*)(wrow + ko + 4);                            \
      bq##S##10 = *(const float4*)(wrow + ko + 32);                           \
      bq##S##11 = *(const float4*)(wrow + ko + 36);                           \
    }

  #define COMPIT(S, IT, ASBUF)                                                \
    {                                                                         \
      bf16x8_t bf;                                                            \
      _Pragma("unroll")                                                       \
      for (int e = 0; e < 4; ++e) {                                           \
        bf[e]     = (short)f2bf(bq##S##IT##0[e]);                             \
        bf[e + 4] = (short)f2bf(bq##S##IT##1[e]);                             \
      }                                                                       \
      _Pragma("unroll")                                                       \
      for (int fm = 0; fm < 16; ++fm) {                                       \
        int row = fm * 16 + lr;                                               \
        int slot = ((IT) * 4 + lg) ^ (row & 7);                               \
        bf16x8_t av = *(const bf16x8_t*)&ASBUF[row * 64 + slot * 8];          \
        acc[fm] = __builtin_amdgcn_mfma_f32_16x16x32_bf16(                    \
            av, bf, acc[fm], 0, 0, 0);                                        \
      }                                                                       \
    }

  #define COMPUTE(S, ASBUF) COMPIT(S, 0, ASBUF) COMPIT(S, 1, ASBUF)

  // ---- prologue ----
  STAGE(0, As0)
  STAGE(1, As1)
  LOADB(A, 0)
  __syncthreads();

  // ---- straight-line main schedule (chunk c reads As[c&1], set A/B alt) ----
  LOADB(B, 1) COMPUTE(A, As0) __syncthreads(); STAGE(2, As0)
  LOADB(A, 2) COMPUTE(B, As1) __syncthreads(); STAGE(3, As1)
  LOADB(B, 3) COMPUTE(A, As0) __syncthreads(); STAGE(4, As0)
  LOADB(A, 4) COMPUTE(B, As1) __syncthreads(); STAGE(5, As1)
  LOADB(B, 5) COMPUTE(A, As0) __syncthreads(); STAGE(6, As0)
  LOADB(A, 6) COMPUTE(B, As1) __syncthreads(); STAGE(7, As1)
  LOADB(B, 7) COMPUTE(A, As0) __syncthreads();
  COMPUTE(B, As1)

  // ---- epilogue: C/D layout col=lane&15, row=(lane>>4)*4+j ----
  unsigned short* p = part + (size_t)kc * (M * NOUT);
  #pragma unroll
  for (int fm = 0; fm < 16; ++fm) {
    #pragma unroll
    for (int j = 0; j < 4; ++j) {
      int row = fm * 16 + lg * 4 + j;
      int col = o0 + lr;
      p[(size_t)row * NOUT + col] = f2bf(acc[fm][j]);
    }
  }
  #undef STAGE
  #undef LOADB
  #undef COMPIT
  #undef COMPUTE
}

// out[b][o] = sum_kc bf2f(part[kc][b][o]) + sum_r bias[o][r]*coef[b][r]
__global__ __launch_bounds__(256) void reduce_bias_kernel(
    const unsigned short* __restrict__ part, const float* __restrict__ bias,
    const float* __restrict__ coef, float* __restrict__ out)
{
  int t = blockIdx.x * 256 + threadIdx.x;
  int idx8 = t * 8;                       // 8 consecutive outputs, same b
  int b = idx8 >> 10, o = idx8 & 1023;

  float s[8];
  #pragma unroll
  for (int j = 0; j < 8; ++j) s[j] = 0.f;

  #pragma unroll
  for (int c = 0; c < NKC; ++c) {
    u16x8_t v = *(const u16x8_t*)(part + (size_t)c * (M * NOUT) + idx8);
    #pragma unroll
    for (int j = 0; j < 8; ++j) s[j] += bf2f(v[j]);
  }

  const f32x4_t* cr = (const f32x4_t*)(coef + (size_t)b * RANK);
  f32x4_t c0 = cr[0], c1 = cr[1], c2 = cr[2], c3 = cr[3];
  #pragma unroll
  for (int j = 0; j < 8; ++j) {
    const f32x4_t* br = (const f32x4_t*)(bias + (size_t)(o + j) * RANK);
    f32x4_t b0 = br[0], b1 = br[1], b2 = br[2], b3 = br[3];
    float bb = 0.f;
    #pragma unroll
    for (int e = 0; e < 4; ++e)
      bb += b0[e] * c0[e] + b1[e] * c1[e] + b2[e] * c2[e] + b3[e] * c3[e];
    s[j] += bb;
  }
  float4* dst = (float4*)(out + idx8);
  dst[0] = make_float4(s[0], s[1], s[2], s[3]);
  dst[1] = make_float4(s[4], s[5], s[6], s[7]);
}

extern "C" void kernel_launch(void* const* d_in, const int* in_sizes, int n_in,
                              void* d_out, int out_size, void* d_ws, size_t ws_size,
                              hipStream_t stream) {
  const float* input = (const float*)d_in[0];   // (256, 1024)
  const float* coef  = (const float*)d_in[1];   // (256, 16)
  const float* W     = (const float*)d_in[2];   // (1024, 1024, 16) -> (1024, 16384)
  const float* bias  = (const float*)d_in[3];   // (1024, 16)
  float* out = (float*)d_out;                   // (256, 1024)

  unsigned short* X    = (unsigned short*)d_ws;                               // 8 MiB bf16
  unsigned short* part = (unsigned short*)((char*)d_ws + (size_t)M * KTOT * 2); // 16 MiB bf16

  build_x_kernel<<<(M * 1024) / 256, 256, 0, stream>>>(input, coef, X);
  gemm_kernel<<<dim3(NTILE, NKC), 256, 0, stream>>>(X, W, part);
  reduce_bias_kernel<<<(M * NOUT) / (256 * 8), 256, 0, stream>>>(part, bias, coef, out);
}